// Round 11
// baseline (141.254 us; speedup 1.0000x reference)
//
#include <hip/hip_runtime.h>
#include <math.h>

// B=16, C_IN=256, C_OUT=256, H=W=64, K=3, NK=2
// weights: [2][256][256][3][3]; bank stride 589824 floats; per-o stride 2304.
//
// Pipeline:
//  1. wprep (fused scale+prep): combined+modulated+demod bf16 weights -> wq,
//     LINEAR-A LDS-image per (b,ot4,c16): [s5][mf4][g4][lm16][e8] (10240 ush),
//     where p = 4s+g = io*10 + j (j=9 zero dummy tap), o = ot*64+mf*16+lm.
//     A-read in conv = base + lane*16 + imm(s*4096+mf*1024) bytes: conflict-free.
//  2. xprep: x -> bf16 xq [b][c16][rowp 66][colp 66][io2][e8], halo zeros,
//     pre-swizzled 2-bit XOR (byte bit7->4, bit8->5) for conflict-light B reads.
//  3. conv_mfma: implicit GEMM mfma_f32_16x16x32_bf16. Block = 256 thr
//     (4 waves, 1 block/CU) = 64 o x 8 rows x 64 px; grid 512 (2 rounds).
//     Wave tile mf4 x nf8: acc 128 (AGPR), frag P/Q double-buffer 96 arch VGPR
//     -> fits the 256 arch budget (R9/R10 spilled / couldn't pipeline).
//     ds_reads for phase s+1 issued BEFORE MFMAs of phase s; GLL staging for
//     c+1 spread over phases 1-4; one covered LGKM0+VM0+barrier per c-step.
//  4. norm_kernel: channel RMSNorm * gamma * 16 + SiLU in place.

typedef __attribute__((ext_vector_type(8))) short short8;
typedef __attribute__((ext_vector_type(4))) float f32x4;

#define GLL16(src, dst)                                                       \
  __builtin_amdgcn_global_load_lds(                                           \
      (const __attribute__((address_space(1))) unsigned int*)(src),           \
      (__attribute__((address_space(3))) unsigned int*)(dst), 16, 0, 0)

static __device__ __forceinline__ unsigned short f2bf(float v) {
  union { float f; unsigned u; } u;
  u.f = v;
  unsigned r = u.u + 0x7FFF + ((u.u >> 16) & 1);  // RNE
  return (unsigned short)(r >> 16);
}

// ---------------------------------------------------------------------------
// Kernel 1: fused weight prep. Grid 512 = b(16) x oq(32 o-octets), 256 thr.
// ---------------------------------------------------------------------------
__global__ __launch_bounds__(256) void wprep(
    const float* __restrict__ mod, const float* __restrict__ kmod,
    const float* __restrict__ weights, unsigned short* __restrict__ wq) {
  int blk = blockIdx.x;  // b*32 + oq
  int b = blk >> 5, oq = blk & 31;
  int t = threadIdx.x;
  int o_l = t >> 5, its = t & 31;
  int o = oq * 8 + o_l;

  float k0 = kmod[b * 2 + 0], k1 = kmod[b * 2 + 1];
  float mx = fmaxf(k0, k1);
  float e0 = expf(k0 - mx), e1 = expf(k1 - mx);
  float ai = 1.0f / (e0 + e1);
  float a0 = e0 * ai, a1 = e1 * ai;

  float wv[9][8];  // [j][e]
  float s = 0.0f;
  const float* w0 = &weights[((size_t)o * 256 + its * 8) * 9];
  const float* w1 = w0 + 589824;
#pragma unroll
  for (int e = 0; e < 8; ++e) {
    float f = mod[b * 256 + its * 8 + e] + 1.0f;
#pragma unroll
    for (int j = 0; j < 9; ++j) {
      float v = (a0 * w0[e * 9 + j] + a1 * w1[e * 9 + j]) * f;
      wv[j][e] = v;
      s = fmaf(v, v, s);
    }
  }

  __shared__ float red[8][32];
  __shared__ float scl[8];
  red[o_l][its] = s;
  __syncthreads();
  if (t < 8) {
    float tot = 0.0f;
#pragma unroll
    for (int k = 0; k < 32; ++k) tot += red[t][k];
    scl[t] = rsqrtf(fmaxf(tot, 1e-8f));
  }
  __syncthreads();
  float sc = scl[o_l];

  int c = its >> 1, io = its & 1;
  int ot = o >> 6, mf = (o & 63) >> 4, lm = o & 15;
  // chunk [s5][mf4][g4][lm16][e8] = 10240 ush; per (b,ot4,c16)
  size_t cbase = ((size_t)(b * 64 + ot * 16 + c)) * 10240;
#pragma unroll
  for (int j = 0; j < 9; ++j) {
    int p = io * 10 + j;
    int sp = p >> 2, g = p & 3;
    short8 pk;
#pragma unroll
    for (int e = 0; e < 8; ++e) pk[e] = (short)f2bf(wv[j][e] * sc);
    *(short8*)(wq + cbase + sp * 2048 + mf * 512 + g * 128 + lm * 8) = pk;
  }
  // dummy-tap zeros: p = 9 (s2,g1) and p = 19 (s4,g3); 8 o x 16 c x 2 io slots
  {
    int c2 = t >> 4, io2 = (t >> 3) & 1, olq = t & 7;
    int o2 = oq * 8 + olq;
    int ot2 = o2 >> 6, mf2 = (o2 & 63) >> 4, lm2 = o2 & 15;
    int p2 = io2 * 10 + 9;
    int sp2 = p2 >> 2, g2 = p2 & 3;
    short8 z = {0, 0, 0, 0, 0, 0, 0, 0};
    *(short8*)(wq + ((size_t)(b * 64 + ot2 * 16 + c2)) * 10240 + sp2 * 2048 +
               mf2 * 512 + g2 * 128 + lm2 * 8) = z;
  }
}

// ---------------------------------------------------------------------------
// Kernel 2: x prep -> bf16 xq, pre-swizzled (2-bit XOR).
// ---------------------------------------------------------------------------
__global__ __launch_bounds__(256) void xprep(
    const float* __restrict__ x, unsigned short* __restrict__ xq) {
  int blk = blockIdx.x;  // (b*16 + c)*66 + rowp
  int rowp = blk % 66;
  int bc = blk / 66;
  int b = bc >> 4, c = bc & 15;
  int t = threadIdx.x;
  size_t obase = (size_t)blk * 1056;

  if (rowp == 0 || rowp == 65) {
    for (int idx = t; idx < 1056; idx += 256) xq[obase + idx] = 0;
    return;
  }
  __shared__ __align__(16) unsigned short xs2[1056];
  int row = rowp - 1;
  for (int idx = t; idx < 1056; idx += 256) xs2[idx] = 0;
  __syncthreads();
#pragma unroll
  for (int k = 0; k < 4; ++k) {
    int idx = t + k * 256;  // 0..1023
    int il = idx >> 6, col = idx & 63;
    float v = x[(((size_t)b * 256 + c * 16 + il) * 64 + row) * 64 + col];
    xs2[(col + 1) * 16 + il] = f2bf(v);
  }
  __syncthreads();
  if (t < 132) {
    int S = 4 * (rowp & 7) + t;
    int fl = ((S >> 3) & 1) | (((S >> 4) & 1) << 1);
    *(short8*)(xq + obase + (size_t)(t ^ fl) * 8) = *(const short8*)&xs2[t * 8];
  }
}

// ---------------------------------------------------------------------------
// Kernel 3: implicit-GEMM conv. 4 waves, mf4 x nf8, acc 128, P/Q frag dbuf.
// Grid 512 (XCD-clustered, 2 rounds/CU).
// ---------------------------------------------------------------------------
__global__ __launch_bounds__(256, 1) void conv_mfma(
    const unsigned short* __restrict__ xq, const unsigned short* __restrict__ wq,
    float* __restrict__ out) {
  __shared__ __align__(16) unsigned short wsm[2][10240];  // [s5][mf4][lane64][e8]
  __shared__ __align__(16) unsigned short xsm[2][10560];  // [rl10][colp66][io2][e8]

  int bid = blockIdx.x;
  int xcd = bid & 7;
  int kk = bid >> 3;            // 0..63
  int b = xcd * 2 + (kk >> 5);  // 2 batches per XCD
  int rem = kk & 31;
  int ot = rem >> 3;  // 64-o quarter
  int rt = rem & 7;   // 8-row tile
  int r0 = rt * 8;

  int t = threadIdx.x;
  int w = t >> 6, lane = t & 63;
  int g = (t >> 4) & 3, lm = t & 15;
  int aoff = lane * 16;  // A-read per-lane byte offset

  // B addresses per phase s for the wave's two rows, swizzled; +nc*512 at use.
  int b0_[5], b1_[5];
#pragma unroll
  for (int s = 0; s < 5; ++s) {
    int p = 4 * s + g;
    int io = (p >= 10) ? 1 : 0;
    int j = p - 10 * io;
    int jd3, jm3;
    if (j == 9) { jd3 = 0; jm3 = 0; }  // dummy tap: weights zero
    else { jd3 = (j >= 3) + (j >= 6); jm3 = j - 3 * jd3; }
    int la0 = ((2 * w + jd3) * 66 + lm + jm3) * 32 + io * 16;
    la0 ^= (((la0 >> 7) & 1) << 4) ^ (((la0 >> 8) & 1) << 5);
    b0_[s] = la0;
    int la1 = ((2 * w + 1 + jd3) * 66 + lm + jm3) * 32 + io * 16;
    la1 ^= (((la1 >> 7) & 1) << 4) ^ (((la1 >> 8) & 1) << 5);
    b1_[s] = la1;
  }

  f32x4 acc[4][8];
#pragma unroll
  for (int mf = 0; mf < 4; ++mf)
#pragma unroll
    for (int nf = 0; nf < 8; ++nf) acc[mf][nf] = (f32x4){0.f, 0.f, 0.f, 0.f};

#define WGLL(cn, nb, r)                                                         \
  {                                                                             \
    const unsigned short* s_ =                                                  \
        wq + ((size_t)(b * 64 + ot * 16 + (cn))) * 10240 + ((r) * 256 + t) * 8; \
    GLL16(s_, &wsm[nb][((r) * 256 + t) * 8]);                                   \
  }
#define XGLL(cn, nb, r)                                                          \
  {                                                                              \
    const unsigned short* s_ =                                                   \
        xq + ((size_t)((b * 16 + (cn)) * 66 + r0)) * 1056 + ((r) * 256 + t) * 8; \
    GLL16(s_, &xsm[nb][((r) * 256 + t) * 8]);                                    \
  }
#define XGLLP(cn, nb)                                                            \
  {                                                                              \
    const unsigned short* s_ =                                                   \
        xq + ((size_t)((b * 16 + (cn)) * 66 + r0)) * 1056 + (1280 + t) * 8;      \
    GLL16(s_, &xsm[nb][(1280 + t) * 8]);                                         \
  }

  short8 PA[4], PB[8], QA[4], QB[8];

#define DSRD(SA, SB, cbuf, s)                                                   \
  {                                                                             \
    const char* wsb_ = (const char*)wsm[cbuf] + aoff;                           \
    const char* xsb_ = (const char*)xsm[cbuf];                                  \
    _Pragma("unroll")                                                           \
    for (int mf = 0; mf < 4; ++mf)                                              \
      SA[mf] = *(const short8*)(wsb_ + (s) * 4096 + mf * 1024);                 \
    _Pragma("unroll")                                                           \
    for (int nc = 0; nc < 4; ++nc) {                                            \
      SB[nc] = *(const short8*)(xsb_ + b0_[s] + nc * 512);                      \
      SB[4 + nc] = *(const short8*)(xsb_ + b1_[s] + nc * 512);                  \
    }                                                                           \
  }

#define MFMA32(SA, SB)                                                          \
  {                                                                             \
    __builtin_amdgcn_s_setprio(1);                                              \
    _Pragma("unroll")                                                           \
    for (int nf = 0; nf < 8; ++nf)                                              \
      _Pragma("unroll")                                                         \
      for (int mf = 0; mf < 4; ++mf)                                            \
        acc[mf][nf] = __builtin_amdgcn_mfma_f32_16x16x32_bf16(                  \
            SA[mf], SB[nf], acc[mf][nf], 0, 0, 0);                              \
    __builtin_amdgcn_s_setprio(0);                                              \
  }

#define SBAR __builtin_amdgcn_sched_barrier(0)
#define LGKM0 asm volatile("s_waitcnt lgkmcnt(0)" ::: "memory")
#define VM0 asm volatile("s_waitcnt vmcnt(0)" ::: "memory")

  // RA0/RB0 hold phase s0 data at body entry; RA1/RB1 are the other set.
#define CBODY(RA0, RB0, RA1, RB1, cb, nb, cn)                                   \
  {                                                                             \
    DSRD(RA1, RB1, cb, 1);                                                      \
    WGLL(cn + 1, nb, 0); WGLL(cn + 1, nb, 1); WGLL(cn + 1, nb, 2);              \
    SBAR;                                                                       \
    MFMA32(RA0, RB0);                                                           \
    DSRD(RA0, RB0, cb, 2);                                                      \
    WGLL(cn + 1, nb, 3); WGLL(cn + 1, nb, 4); XGLL(cn + 1, nb, 0);              \
    SBAR;                                                                       \
    MFMA32(RA1, RB1);                                                           \
    DSRD(RA1, RB1, cb, 3);                                                      \
    XGLL(cn + 1, nb, 1); XGLL(cn + 1, nb, 2);                                   \
    SBAR;                                                                       \
    MFMA32(RA0, RB0);                                                           \
    DSRD(RA0, RB0, cb, 4);                                                      \
    XGLL(cn + 1, nb, 3); XGLL(cn + 1, nb, 4);                                   \
    if (t < 40) XGLLP(cn + 1, nb);                                              \
    SBAR;                                                                       \
    MFMA32(RA1, RB1);                                                           \
    LGKM0; SBAR;                                                                \
    VM0;                                                                        \
    __builtin_amdgcn_s_barrier();                                               \
    SBAR;                                                                       \
    DSRD(RA1, RB1, nb, 0); SBAR;                                                \
    MFMA32(RA0, RB0);                                                           \
  }

#define CTAIL(RA0, RB0, RA1, RB1, cb)                                           \
  {                                                                             \
    DSRD(RA1, RB1, cb, 1); SBAR; MFMA32(RA0, RB0);                              \
    DSRD(RA0, RB0, cb, 2); SBAR; MFMA32(RA1, RB1);                              \
    DSRD(RA1, RB1, cb, 3); SBAR; MFMA32(RA0, RB0);                              \
    DSRD(RA0, RB0, cb, 4); SBAR; MFMA32(RA1, RB1);                              \
    MFMA32(RA0, RB0);                                                           \
  }

  // prologue: stage c=0 into buffer 0; preload P = R(c0, s0)
  WGLL(0, 0, 0); WGLL(0, 0, 1); WGLL(0, 0, 2); WGLL(0, 0, 3); WGLL(0, 0, 4);
  XGLL(0, 0, 0); XGLL(0, 0, 1); XGLL(0, 0, 2); XGLL(0, 0, 3); XGLL(0, 0, 4);
  if (t < 40) XGLLP(0, 0);
  VM0;
  __builtin_amdgcn_s_barrier();
  SBAR;
  DSRD(PA, PB, 0, 0);
  SBAR;

  for (int cc = 0; cc < 16; cc += 2) {
    CBODY(PA, PB, QA, QB, 0, 1, cc);
    if (cc < 14) {
      CBODY(QA, QB, PA, PB, 1, 0, cc + 1);
    } else {
      CTAIL(QA, QB, PA, PB, 1);
    }
  }

  // ---- epilogue: D col=lane&15 (px within 16), row-in-frag=g*4+q (o) ----
#pragma unroll
  for (int mf = 0; mf < 4; ++mf)
#pragma unroll
    for (int nf = 0; nf < 8; ++nf) {
      int row = r0 + 2 * w + (nf >> 2);
      int col = (nf & 3) * 16 + lm;
#pragma unroll
      for (int q = 0; q < 4; ++q) {
        int o = ot * 64 + mf * 16 + g * 4 + q;
        out[(((size_t)b * 256 + o) * 64 + row) * 64 + col] = acc[mf][nf][q];
      }
    }
#undef WGLL
#undef XGLL
#undef XGLLP
#undef DSRD
#undef MFMA32
#undef SBAR
#undef LGKM0
#undef VM0
#undef CBODY
#undef CTAIL
}

// ---------------------------------------------------------------------------
// Kernel 4: channel RMSNorm * gamma * 16 + SiLU, in place.
// ---------------------------------------------------------------------------
__global__ __launch_bounds__(256) void norm_kernel(
    float* __restrict__ y, const float* __restrict__ gamma) {
  int blk = blockIdx.x;
  int b = blk >> 6, h = blk & 63;
  int t = threadIdx.x;
  int p = t & 63, og = t >> 6;

  size_t base = (((size_t)b * 256) * 64 + h) * 64 + p;
  float yv[64];
  float s = 0.0f;
#pragma unroll
  for (int k = 0; k < 64; k++) {
    yv[k] = y[base + (size_t)(og * 64 + k) * 4096];
    s = fmaf(yv[k], yv[k], s);
  }

  __shared__ float red[4][64];
  __shared__ float invs[64];
  red[og][p] = s;
  __syncthreads();
  if (og == 0) {
    float tot = red[0][p] + red[1][p] + red[2][p] + red[3][p];
    float nrm = sqrtf(tot);
    invs[p] = 16.0f / fmaxf(nrm, 1e-12f);
  }
  __syncthreads();
  float iv = invs[p];
#pragma unroll
  for (int k = 0; k < 64; k++) {
    int o = og * 64 + k;
    float v = yv[k] * iv * gamma[o];
    float sg = 1.0f / (1.0f + expf(-v));
    y[base + (size_t)o * 4096] = v * sg;
  }
}

extern "C" void kernel_launch(void* const* d_in, const int* in_sizes, int n_in,
                              void* d_out, int out_size, void* d_ws, size_t ws_size,
                              hipStream_t stream) {
  const float* x = (const float*)d_in[0];
  const float* mod = (const float*)d_in[1];
  const float* kmod = (const float*)d_in[2];
  const float* weights = (const float*)d_in[3];
  const float* gamma = (const float*)d_in[4];
  float* out = (float*)d_out;

  // ws layout: wq 20,971,520 B | (gap) | xq 35,684,352 B  (~56.7 MB)
  unsigned short* wq = (unsigned short*)d_ws;
  unsigned short* xq = (unsigned short*)((char*)d_ws + 20987904);

  wprep<<<512, 256, 0, stream>>>(mod, kmod, weights, wq);
  xprep<<<16 * 16 * 66, 256, 0, stream>>>(x, xq);
  conv_mfma<<<512, 256, 0, stream>>>(xq, wq, out);
  norm_kernel<<<16 * 64, 256, 0, stream>>>(out, gamma);
}